// Round 1
// baseline (766.152 us; speedup 1.0000x reference)
//
#include <hip/hip_runtime.h>
#include <hip/hip_bf16.h>

// Problem constants
#define BB   2048
#define TT   240
#define DD   90
#define MM   (BB*TT)        // 491520 rows of x / h
#define KDIM (TT*DD)        // 21600
#define NCLS 40
#define NP   288            // packed gate cols: 3 live gates (i,g,o) * 96 (90 padded)
#define K2SPLIT 5
#define KCH  (KDIM/K2SPLIT) // 4320 (4320/32 = 135 exact)

__device__ __forceinline__ float sigm(float x){ return 1.0f/(1.0f + __expf(-x)); }
__device__ __forceinline__ float tanh_f(float x){ return 1.0f - 2.0f/(1.0f + __expf(2.0f*x)); }

// ---------------------------------------------------------------------------
// pack: WTp[k2][c][2] = W_ih[gate_row(c)][2*k2 + {0,1}], c = g*96 + dd (dd<90)
// gate rows: i -> dd, g -> 180+dd, o -> 270+dd  (f gate is dead: f*c0 == 0)
// bsum[c] = b_ih[row] + b_hh[row]
// ---------------------------------------------------------------------------
__global__ void pack_kernel(const float* __restrict__ Wih,
                            const float* __restrict__ bih,
                            const float* __restrict__ bhh,
                            float* __restrict__ WTp,
                            float* __restrict__ bsum)
{
    int gid = blockIdx.x*256 + threadIdx.x;
    if (gid < 45*NP){
        int c  = gid % NP;
        int k2 = gid / NP;
        int g  = c / 96, dd = c % 96;
        float v0 = 0.f, v1 = 0.f;
        if (dd < 90){
            int row = (g==0 ? dd : (g==1 ? 180+dd : 270+dd));
            v0 = Wih[row*90 + 2*k2    ];
            v1 = Wih[row*90 + 2*k2 + 1];
        }
        WTp[gid*2+0] = v0;
        WTp[gid*2+1] = v1;
    }
    if (gid < NP){
        int g = gid/96, dd = gid%96;
        float bv = 0.f;
        if (dd < 90){
            int row = (g==0 ? dd : (g==1 ? 180+dd : 270+dd));
            bv = bih[row] + bhh[row];
        }
        bsum[gid] = bv;
    }
}

// ---------------------------------------------------------------------------
// k1: gates GEMM + activations -> h (bf16).
// Block: 64 rows of x in LDS. 256 threads = 32 d-lanes x 8 row-groups.
// Thread register tile: 8 rows x (3 d-cols x 3 gates) = 72 accumulators.
// ---------------------------------------------------------------------------
__global__ __launch_bounds__(256)
void k1_gates(const float* __restrict__ x,
              const float* __restrict__ WTp,
              const float* __restrict__ bsum,
              __hip_bfloat16* __restrict__ h)
{
    __shared__ float xs[64*90];

    const int tid = threadIdx.x;
    const long m0 = (long)blockIdx.x * 64;

    // stage x tile: 64 rows * 90 f32 are contiguous in global -> flat float4 copy
    const float4* xg  = (const float4*)(x + m0*90);
    float4*       xs4 = (float4*)xs;
    #pragma unroll
    for (int i = 0; i < 6; ++i){
        int idx = tid + i*256;
        if (idx < 1440) xs4[idx] = xg[idx];
    }
    __syncthreads();

    const int tx = tid & 31;   // d = tx + 32*j, j = 0..2
    const int ty = tid >> 5;   // rows = ty + 8*i, i = 0..7

    float acc[8][9];
    #pragma unroll
    for (int i=0;i<8;++i)
        #pragma unroll
        for (int c=0;c<9;++c) acc[i][c] = 0.f;

    const float2* WT2 = (const float2*)WTp;
    for (int k2 = 0; k2 < 45; ++k2){
        float2 wv[9];
        #pragma unroll
        for (int g=0; g<3; ++g)
            #pragma unroll
            for (int j=0; j<3; ++j)
                wv[g*3+j] = WT2[k2*NP + g*96 + j*32 + tx];
        #pragma unroll
        for (int i=0; i<8; ++i){
            float2 xv = *(const float2*)(&xs[(ty + 8*i)*90 + 2*k2]);
            #pragma unroll
            for (int c=0; c<9; ++c){
                acc[i][c] = fmaf(xv.x, wv[c].x, acc[i][c]);
                acc[i][c] = fmaf(xv.y, wv[c].y, acc[i][c]);
            }
        }
    }

    float bv[9];
    #pragma unroll
    for (int g=0; g<3; ++g)
        #pragma unroll
        for (int j=0; j<3; ++j)
            bv[g*3+j] = bsum[g*96 + j*32 + tx];

    #pragma unroll
    for (int i=0; i<8; ++i){
        long m = m0 + ty + 8*i;
        #pragma unroll
        for (int j=0; j<3; ++j){
            int d = tx + 32*j;
            if (d < 90){
                float gi = acc[i][0+j] + bv[0+j];
                float gg = acc[i][3+j] + bv[3+j];
                float go = acc[i][6+j] + bv[6+j];
                float cc = sigm(gi) * tanh_f(gg);
                float hv = sigm(go) * tanh_f(cc);
                h[m*90 + d] = __float2bfloat16(hv);
            }
        }
    }
}

// ---------------------------------------------------------------------------
// k2: out partials. Block = 8 b's x 32 k-lanes, split-K over blockIdx.y (5).
// Each thread: 40 accumulators over its k-stripe; shuffle-reduce width 32.
// ---------------------------------------------------------------------------
__global__ __launch_bounds__(256)
void k2_out(const __hip_bfloat16* __restrict__ h,
            const float* __restrict__ W2,
            float* __restrict__ part)
{
    const int tid = threadIdx.x;
    const int tb  = tid >> 5;          // 0..7 -> b
    const int tk  = tid & 31;          // k lane
    const int b   = blockIdx.x*8 + tb;
    const int ks  = blockIdx.y;

    const long hbase = (long)b*KDIM + (long)ks*KCH + tk;
    const long wbase = (long)ks*KCH + tk;

    float acc[NCLS];
    #pragma unroll
    for (int n=0; n<NCLS; ++n) acc[n] = 0.f;

    for (int j = 0; j < KCH/32; ++j){
        float hv = __bfloat162float(h[hbase + j*32]);
        const float* wp = W2 + wbase + j*32;
        #pragma unroll
        for (int n=0; n<NCLS; ++n)
            acc[n] = fmaf(hv, wp[(long)n*KDIM], acc[n]);
    }

    #pragma unroll
    for (int n=0; n<NCLS; ++n){
        #pragma unroll
        for (int m=16; m>=1; m>>=1)
            acc[n] += __shfl_xor(acc[n], m, 32);
    }

    if (tk == 0){
        float* pp = part + ((long)ks*BB + b)*NCLS;
        #pragma unroll
        for (int n=0; n<NCLS; ++n) pp[n] = acc[n];
    }
}

// ---------------------------------------------------------------------------
// k3: reduce split-K partials + bias, then softmax over each group of 10.
// ---------------------------------------------------------------------------
__global__ void k3_softmax(const float* __restrict__ part,
                           const float* __restrict__ bout,
                           float* __restrict__ out)
{
    int b = blockIdx.x*256 + threadIdx.x;
    if (b >= BB) return;

    float v[NCLS];
    #pragma unroll
    for (int n=0; n<NCLS; ++n){
        float s = bout[n];
        #pragma unroll
        for (int ks=0; ks<K2SPLIT; ++ks)
            s += part[((long)ks*BB + b)*NCLS + n];
        v[n] = s;
    }

    #pragma unroll
    for (int g=0; g<4; ++g){
        float mx = v[g*10];
        #pragma unroll
        for (int q=1; q<10; ++q) mx = fmaxf(mx, v[g*10+q]);
        float e[10]; float s = 0.f;
        #pragma unroll
        for (int q=0; q<10; ++q){ e[q] = __expf(v[g*10+q] - mx); s += e[q]; }
        float inv = 1.0f/s;
        #pragma unroll
        for (int q=0; q<10; ++q) out[(long)b*NCLS + g*10 + q] = e[q]*inv;
    }
}

// ---------------------------------------------------------------------------
extern "C" void kernel_launch(void* const* d_in, const int* in_sizes, int n_in,
                              void* d_out, int out_size, void* d_ws, size_t ws_size,
                              hipStream_t stream)
{
    const float* x    = (const float*)d_in[0];
    const float* Wih  = (const float*)d_in[1];
    // d_in[2] = W_hh: unused (zero initial hidden state -> W_hh @ h0 == 0)
    const float* bih  = (const float*)d_in[3];
    const float* bhh  = (const float*)d_in[4];
    const float* W2   = (const float*)d_in[5];
    const float* bout = (const float*)d_in[6];
    float* out = (float*)d_out;

    char* ws = (char*)d_ws;
    size_t off = 0;
    __hip_bfloat16* h = (__hip_bfloat16*)(ws + off);              // 88,473,600 B
    off += (size_t)MM * DD * sizeof(__hip_bfloat16);
    off  = (off + 255) & ~(size_t)255;
    float* part = (float*)(ws + off);                              // 1,638,400 B
    off += (size_t)K2SPLIT * BB * NCLS * sizeof(float);
    off  = (off + 255) & ~(size_t)255;
    float* WTp = (float*)(ws + off);                               // 103,680 B
    off += (size_t)45 * NP * 2 * sizeof(float);
    off  = (off + 255) & ~(size_t)255;
    float* bsum = (float*)(ws + off);
    off += (size_t)NP * sizeof(float);

    pack_kernel<<<51, 256, 0, stream>>>(Wih, bih, bhh, WTp, bsum);
    k1_gates<<<MM/64, 256, 0, stream>>>(x, WTp, bsum, h);
    dim3 g2(BB/8, K2SPLIT);
    k2_out<<<g2, 256, 0, stream>>>(h, W2, part);
    k3_softmax<<<(BB+255)/256, 256, 0, stream>>>(part, bout, out);
}

// Round 3
// 177.872 us; speedup vs baseline: 4.3073x; 4.3073x over previous
//
#include <hip/hip_runtime.h>
#include <hip/hip_bf16.h>

#define BB   2048
#define TT   240
#define DD   90
#define MM   (BB*TT)          // 491520
#define KDIM (TT*DD)          // 21600
#define NCLS 40
#define NPAD 48               // k2 N padded to 3 MFMA col-tiles
#define KS2  45               // k2 split-K chunks
#define KST  15               // k-steps (x32) per chunk: 45*15*32 = 21600

typedef __bf16 bf16x8 __attribute__((ext_vector_type(8)));
typedef float  f32x4  __attribute__((ext_vector_type(4)));

__device__ __forceinline__ float sigm(float v){ return 1.0f/(1.0f + __expf(-v)); }
__device__ __forceinline__ float tanh_f(float v){ return 1.0f - 2.0f/(1.0f + __expf(2.0f*v)); }

// ---------------------------------------------------------------------------
// pack1: Wtb[c][k] bf16, c = g*96+dd (gates i,g,o), k padded 90->104 w/ zeros.
//        bsum[c] = b_ih[row]+b_hh[row].
// ---------------------------------------------------------------------------
__global__ void pack1(const float* __restrict__ Wih,
                      const float* __restrict__ bih,
                      const float* __restrict__ bhh,
                      __bf16* __restrict__ wtb,
                      float* __restrict__ bsum)
{
    int id = blockIdx.x*256 + threadIdx.x;
    if (id < 288*13){
        int c  = id / 13;
        int k8 = id - c*13;
        int g  = c / 96, dd = c - g*96;
        int row = (g==0 ? dd : (g==1 ? 180+dd : 270+dd));
        bf16x8 v;
        #pragma unroll
        for (int e = 0; e < 8; ++e){
            int k = k8*8 + e;
            float f = (dd < 90 && k < 90) ? Wih[row*90 + k] : 0.f;
            v[e] = (__bf16)f;
        }
        *(bf16x8*)(wtb + c*104 + k8*8) = v;
    }
    if (id < 288){
        int g = id / 96, dd = id - g*96;
        float bv = 0.f;
        if (dd < 90){
            int row = (g==0 ? dd : (g==1 ? 180+dd : 270+dd));
            bv = bih[row] + bhh[row];
        }
        bsum[id] = bv;
    }
}

// ---------------------------------------------------------------------------
// pack2: hi/lo bf16 split of W_out: w = hi + lo removes the systematic
// quantization error (shared across all 21600 summands per class).
// [48][21600] each, n padded 40->48 with zeros.
// ---------------------------------------------------------------------------
__global__ void pack2(const float* __restrict__ W2,
                      __bf16* __restrict__ w2hi,
                      __bf16* __restrict__ w2lo)
{
    int id = blockIdx.x*256 + threadIdx.x;
    if (id >= NPAD*2700) return;
    int n  = id / 2700;
    int k8 = id - n*2700;
    bf16x8 vh, vl;
    if (n < NCLS){
        #pragma unroll
        for (int e = 0; e < 8; ++e){
            float f = W2[(size_t)n*KDIM + k8*8 + e];
            __bf16 hb = (__bf16)f;
            vh[e] = hb;
            vl[e] = (__bf16)(f - (float)hb);
        }
    } else {
        #pragma unroll
        for (int e = 0; e < 8; ++e){ vh[e] = (__bf16)0.f; vl[e] = (__bf16)0.f; }
    }
    *(bf16x8*)(w2hi + (size_t)n*KDIM + k8*8) = vh;
    *(bf16x8*)(w2lo + (size_t)n*KDIM + k8*8) = vl;
}

// ---------------------------------------------------------------------------
// k1: gates GEMM via MFMA. 256 persistent blocks (1/CU), 512 thr = 8 waves.
// W in LDS once per block; 15 x-tiles of 128 rows, reg-staged prefetch.
// Wave w owns M-tile rows [w*16, w*16+16); N = 288 = 18 tiles; K = 96 = 3 steps.
// ---------------------------------------------------------------------------
__global__ __launch_bounds__(512, 2)
void k1_gates(const float* __restrict__ x,
              const __bf16* __restrict__ wtb,
              const float* __restrict__ bsum,
              __bf16* __restrict__ h)
{
    __shared__ __align__(16) __bf16 wt[288*104];   // 59904 B
    __shared__ __align__(16) __bf16 xs[128*104];   // 26624 B

    const int tid  = threadIdx.x;
    const int lane = tid & 63;
    const int wv   = tid >> 6;      // 0..7
    const int l15  = lane & 15;
    const int kg   = lane >> 4;     // 0..3

    // stage W tile (bf16, already packed/padded) -> LDS
    {
        const float4* src = (const float4*)wtb;
        float4* dst = (float4*)wt;
        #pragma unroll
        for (int i = 0; i < 8; ++i){
            int idx = tid + i*512;
            if (idx < 3744) dst[idx] = src[idx];
        }
    }
    // zero-pad xs cols 90..95 ONCE (copy loop below never touches cols >= 90)
    if (tid < 384){
        int r = tid / 3, q = tid - r*3;
        *(unsigned int*)(xs + r*104 + 90 + q*2) = 0u;
    }

    // per-lane biases (loop-invariant): c = g*96 + dd, dd = nt*16 + l15
    float bias_i[6], bias_g[6], bias_o[6];
    #pragma unroll
    for (int nt = 0; nt < 6; ++nt){
        int dd = nt*16 + l15;
        bool ok = dd < 90;
        bias_i[nt] = ok ? bsum[dd]      : 0.f;
        bias_g[nt] = ok ? bsum[96+dd]   : 0.f;
        bias_o[nt] = ok ? bsum[192+dd]  : 0.f;
    }

    const int t0 = blockIdx.x * 15;        // 256 blocks * 15 tiles = 3840

    // preload x tile 0 into regs (128 rows * 45 float2 = 5760)
    float2 xr[12];
    {
        const float2* xg = (const float2*)(x + (size_t)t0 * (128*90));
        #pragma unroll
        for (int i = 0; i < 12; ++i){
            int p = tid + i*512;
            xr[i] = (p < 5760) ? xg[p] : make_float2(0.f, 0.f);
        }
    }

    for (int t = 0; t < 15; ++t){
        __syncthreads();                   // xs free (all waves done computing)
        // regs -> LDS (f32 -> bf16 pair-packed b32 writes); exact div by 45
        #pragma unroll
        for (int i = 0; i < 12; ++i){
            unsigned p = (unsigned)(tid + i*512);
            if (p < 5760u){
                unsigned r  = p / 45u;     // compiler magic-mul: exact
                unsigned c2 = p - r*45u;
                unsigned int u0 = (unsigned int)__builtin_bit_cast(unsigned short, (__bf16)xr[i].x);
                unsigned int u1 = (unsigned int)__builtin_bit_cast(unsigned short, (__bf16)xr[i].y);
                *(unsigned int*)(xs + r*104 + c2*2) = u0 | (u1 << 16);
            }
        }
        __syncthreads();                   // xs ready

        // issue next tile's global loads early: HBM latency hides under MFMA
        if (t < 14){
            const float2* xg = (const float2*)(x + (size_t)(t0 + t + 1) * (128*90));
            #pragma unroll
            for (int i = 0; i < 12; ++i){
                int p = tid + i*512;
                if (p < 5760) xr[i] = xg[p];
            }
        }

        // A-frags: row = l15 (within wave's M-tile), k = ks*32 + 8*kg + e
        const __bf16* xrow = xs + (wv*16 + l15)*104 + 8*kg;
        bf16x8 af[3];
        #pragma unroll
        for (int ks = 0; ks < 3; ++ks)
            af[ks] = *(const bf16x8*)(xrow + ks*32);

        f32x4 acc[18];
        #pragma unroll
        for (int nt = 0; nt < 18; ++nt) acc[nt] = f32x4{0.f,0.f,0.f,0.f};

        #pragma unroll
        for (int nt = 0; nt < 18; ++nt){
            const __bf16* wrow = wt + (nt*16 + l15)*104 + 8*kg;
            #pragma unroll
            for (int ks = 0; ks < 3; ++ks){
                bf16x8 bfr = *(const bf16x8*)(wrow + ks*32);
                acc[nt] = __builtin_amdgcn_mfma_f32_16x16x32_bf16(af[ks], bfr, acc[nt], 0, 0, 0);
            }
        }

        // epilogue: gates i/g/o at acc[nt], acc[nt+6], acc[nt+12], same lane
        const size_t m0 = (size_t)(t0 + t)*128 + wv*16 + kg*4;  // C row = 4*kg + r
        #pragma unroll
        for (int nt = 0; nt < 6; ++nt){
            int dd = nt*16 + l15;
            if (dd < 90){
                #pragma unroll
                for (int r = 0; r < 4; ++r){
                    float gi = acc[nt][r]    + bias_i[nt];
                    float gg = acc[nt+6][r]  + bias_g[nt];
                    float go = acc[nt+12][r] + bias_o[nt];
                    float cc = sigm(gi)*tanh_f(gg);
                    float hv = sigm(go)*tanh_f(cc);
                    h[(m0 + r)*90 + dd] = (__bf16)hv;
                }
            }
        }
    }
}

// ---------------------------------------------------------------------------
// k2: out GEMM [2048 x 21600] @ [21600 x 48] via MFMA, split-K 45.
// Block = 4 waves; wave owns 2 M-tiles (32 b-rows) x 48 cols x 15 k-steps.
// A-frags direct from global h; B = W_out hi + lo (compensated bf16).
// ---------------------------------------------------------------------------
__global__ __launch_bounds__(256)
void k2_out(const __bf16* __restrict__ h,
            const __bf16* __restrict__ w2hi,
            const __bf16* __restrict__ w2lo,
            float* __restrict__ part2)
{
    const int tid  = threadIdx.x;
    const int lane = tid & 63;
    const int wv   = tid >> 6;
    const int l15  = lane & 15;
    const int kg   = lane >> 4;
    const int m0   = (blockIdx.x*4 + wv) * 32;       // 0..2016
    const int chunk= blockIdx.y;                     // 0..44
    const size_t kbase = (size_t)chunk*(KST*32) + 8*kg;

    const __bf16* ha = h    + (size_t)(m0 + l15)*KDIM + kbase;
    const __bf16* hb = ha   + (size_t)16*KDIM;
    const __bf16* h0 = w2hi + (size_t)l15*KDIM + kbase;
    const __bf16* h1 = h0   + (size_t)16*KDIM;
    const __bf16* h2 = h0   + (size_t)32*KDIM;
    const __bf16* l0 = w2lo + (size_t)l15*KDIM + kbase;
    const __bf16* l1 = l0   + (size_t)16*KDIM;
    const __bf16* l2 = l0   + (size_t)32*KDIM;

    f32x4 acc00 = {0.f,0.f,0.f,0.f}, acc01 = acc00, acc02 = acc00;
    f32x4 acc10 = acc00, acc11 = acc00, acc12 = acc00;

    #pragma unroll
    for (int s = 0; s < KST; ++s){
        bf16x8 a0  = *(const bf16x8*)(ha + s*32);
        bf16x8 a1  = *(const bf16x8*)(hb + s*32);
        bf16x8 bh0 = *(const bf16x8*)(h0 + s*32);
        bf16x8 bh1 = *(const bf16x8*)(h1 + s*32);
        bf16x8 bh2 = *(const bf16x8*)(h2 + s*32);
        bf16x8 bl0 = *(const bf16x8*)(l0 + s*32);
        bf16x8 bl1 = *(const bf16x8*)(l1 + s*32);
        bf16x8 bl2 = *(const bf16x8*)(l2 + s*32);
        acc00 = __builtin_amdgcn_mfma_f32_16x16x32_bf16(a0, bh0, acc00, 0,0,0);
        acc01 = __builtin_amdgcn_mfma_f32_16x16x32_bf16(a0, bh1, acc01, 0,0,0);
        acc02 = __builtin_amdgcn_mfma_f32_16x16x32_bf16(a0, bh2, acc02, 0,0,0);
        acc10 = __builtin_amdgcn_mfma_f32_16x16x32_bf16(a1, bh0, acc10, 0,0,0);
        acc11 = __builtin_amdgcn_mfma_f32_16x16x32_bf16(a1, bh1, acc11, 0,0,0);
        acc12 = __builtin_amdgcn_mfma_f32_16x16x32_bf16(a1, bh2, acc12, 0,0,0);
        acc00 = __builtin_amdgcn_mfma_f32_16x16x32_bf16(a0, bl0, acc00, 0,0,0);
        acc01 = __builtin_amdgcn_mfma_f32_16x16x32_bf16(a0, bl1, acc01, 0,0,0);
        acc02 = __builtin_amdgcn_mfma_f32_16x16x32_bf16(a0, bl2, acc02, 0,0,0);
        acc10 = __builtin_amdgcn_mfma_f32_16x16x32_bf16(a1, bl0, acc10, 0,0,0);
        acc11 = __builtin_amdgcn_mfma_f32_16x16x32_bf16(a1, bl1, acc11, 0,0,0);
        acc12 = __builtin_amdgcn_mfma_f32_16x16x32_bf16(a1, bl2, acc12, 0,0,0);
    }

    float* pp = part2 + (size_t)chunk*(BB*NPAD);
    const int rbase = kg*4;
    #pragma unroll
    for (int r = 0; r < 4; ++r){
        size_t row0 = (size_t)(m0 + rbase + r)*NPAD;
        size_t row1 = (size_t)(m0 + 16 + rbase + r)*NPAD;
        pp[row0 +      l15] = acc00[r];
        pp[row0 + 16 + l15] = acc01[r];
        pp[row0 + 32 + l15] = acc02[r];
        pp[row1 +      l15] = acc10[r];
        pp[row1 + 16 + l15] = acc11[r];
        pp[row1 + 32 + l15] = acc12[r];
    }
}

// ---------------------------------------------------------------------------
// k3a: reduce split-K partials + bias -> logits [2048][48] (coalesced)
// ---------------------------------------------------------------------------
__global__ void k3a(const float* __restrict__ part2,
                    const float* __restrict__ bout,
                    float* __restrict__ logits)
{
    int g = blockIdx.x*256 + threadIdx.x;            // < 2048*48
    float s = 0.f;
    for (int c = 0; c < KS2; ++c) s += part2[(size_t)c*(BB*NPAD) + g];
    int n = g % NPAD;
    logits[g] = s + (n < NCLS ? bout[n] : 0.f);
}

// ---------------------------------------------------------------------------
// k3b: softmax over each group of 10
// ---------------------------------------------------------------------------
__global__ void k3b(const float* __restrict__ logits, float* __restrict__ out)
{
    int b = blockIdx.x*256 + threadIdx.x;
    if (b >= BB) return;
    const float* lg = logits + (size_t)b*NPAD;
    #pragma unroll
    for (int g = 0; g < 4; ++g){
        float v[10]; float mx = -1e30f;
        #pragma unroll
        for (int q = 0; q < 10; ++q){ v[q] = lg[g*10+q]; mx = fmaxf(mx, v[q]); }
        float e[10]; float s = 0.f;
        #pragma unroll
        for (int q = 0; q < 10; ++q){ e[q] = __expf(v[q]-mx); s += e[q]; }
        float inv = 1.0f/s;
        #pragma unroll
        for (int q = 0; q < 10; ++q) out[(size_t)b*NCLS + g*10 + q] = e[q]*inv;
    }
}

// ---------------------------------------------------------------------------
extern "C" void kernel_launch(void* const* d_in, const int* in_sizes, int n_in,
                              void* d_out, int out_size, void* d_ws, size_t ws_size,
                              hipStream_t stream)
{
    const float* x    = (const float*)d_in[0];
    const float* Wih  = (const float*)d_in[1];
    // d_in[2] = W_hh unused (zero initial hidden state)
    const float* bih  = (const float*)d_in[3];
    const float* bhh  = (const float*)d_in[4];
    const float* W2   = (const float*)d_in[5];
    const float* bout = (const float*)d_in[6];
    float* out = (float*)d_out;

    char* ws = (char*)d_ws;
    size_t off = 0;
    auto alloc = [&](size_t bytes){ void* p = ws + off; off = (off + bytes + 255) & ~(size_t)255; return p; };
    __bf16* h     = (__bf16*)alloc((size_t)MM*DD*2);           // 88.5 MB
    float*  part2 = (float*) alloc((size_t)KS2*BB*NPAD*4);     // 17.7 MB
    float*  logits= (float*) alloc((size_t)BB*NPAD*4);         // 0.4 MB
    __bf16* wtb   = (__bf16*)alloc(288*104*2);                 // 60 KB
    float*  bsum  = (float*) alloc(288*4);
    __bf16* w2hi  = (__bf16*)alloc((size_t)NPAD*KDIM*2);       // 2.1 MB
    __bf16* w2lo  = (__bf16*)alloc((size_t)NPAD*KDIM*2);       // 2.1 MB

    pack1<<<15, 256, 0, stream>>>(Wih, bih, bhh, wtb, bsum);
    pack2<<<(NPAD*2700 + 255)/256, 256, 0, stream>>>(W2, w2hi, w2lo);
    k1_gates<<<256, 512, 0, stream>>>(x, wtb, bsum, h);
    k2_out<<<dim3(16, KS2), 256, 0, stream>>>(h, w2hi, w2lo, part2);
    k3a<<<(BB*NPAD)/256, 256, 0, stream>>>(part2, bout, logits);
    k3b<<<(BB + 255)/256, 256, 0, stream>>>(logits, out);
}